// Round 13
// baseline (295.795 us; speedup 1.0000x reference)
//
#include <hip/hip_runtime.h>
#include <hip/hip_bf16.h>

// ===================== Round 21: 4-deep all-DMA pipeline, counted vmcnt ========
// R20 post-mortem: L1-bytes model dead (0.67x bytes -> 1.19x time). Surviving
// invariant: every variant idles (all pipes <=15%) at ~1 TB/s effective; all
// had effective prefetch depth ~1 (syncthreads drains; reg-staging serializes
// on STAGE->ISSUE; counted-vmcnt rounds never ran). s_waitcnt CANNOT hang
// (outstanding drains monotonically), barriers are uniform -> R15/16 failures
// were infra-suspect; R17 validated DMA map + XOR swizzle + cvt-on-read on HW.
// Design: BK=32; per 16KB set: A fp32 64x32 (8 DMA units) + B = 8 pre-swizzled
// W fragments (8 units). ALL in-loop vmem = DMA, 4/wave/step, fixed count.
// 4 sets = 64KB static -> 2 blocks/CU. One barrier/step:
//   s_waitcnt vmcnt(N) lgkmcnt(0); s_barrier; sched_barrier(0);
//   issue D(t+3) -> set freed last step; compute set t.
// N: 8 steady (2 newer sets x 4 ops), 4 at NT-2, 0 at last. In-flight ~64KB/CU.
// B reads lane-contiguous (0 conflicts); A reads <=2-way (R17 swizzle).
// Main loop k<3072 (96 steps split 48/48 over kidx); kc=96 reg tail (kidx=1);
// kc=97 zero-W. Epilogue: atomics + gen_W zero-pass (R11, proven).
// Predicted: gemm 40-70us, MfmaUtil 20-40%, FETCH ~105MB, WRITE ~38MB,
// absmax 0.001953125. Container fails => family condemned, revert R18.

#define NFFT   512
#define HOP    128
#define KDIM   3084      // 257*6*2
#define KP     3136      // K padded (49*64) — W layout only
#define NOUT   600
#define NP     640       // W rows padded (5*128)
#define BM     64
#define BN     128
#define NT     48        // BK=32 steps per block (48*32 = 1536 = half of 3072)

#define NFRAG_K 98       // KP/32 k-chunks
#define FRAG_SH 512      // shorts per fragment (64 lanes x 8)
#define WTOT    ((size_t)(NP / 16) * NFRAG_K * FRAG_SH)  // 4.01 MB
#define GRIDB   (128 * 5 * 2)   // 1280

typedef short s16x8 __attribute__((ext_vector_type(8)));
typedef float f32x4 __attribute__((ext_vector_type(4)));

static __device__ __forceinline__ unsigned short bf16_bits(float f) {
    __hip_bfloat16 b = __float2bfloat16(f);   // RNE - R4-verified path
    return *(unsigned short*)&b;
}

static __device__ __forceinline__ s16x8 cvt_frag(float4 lo, float4 hi) {
    s16x8 r;
    r[0] = (short)bf16_bits(lo.x); r[1] = (short)bf16_bits(lo.y);
    r[2] = (short)bf16_bits(lo.z); r[3] = (short)bf16_bits(lo.w);
    r[4] = (short)bf16_bits(hi.x); r[5] = (short)bf16_bits(hi.y);
    r[6] = (short)bf16_bits(hi.z); r[7] = (short)bf16_bits(hi.w);
    return r;
}

// async global->LDS DMA, 16B/lane, dest = wave-uniform base + lane*16 (HW)
static __device__ __forceinline__ void gload_lds16(const void* g, void* l) {
    __builtin_amdgcn_global_load_lds(
        (const __attribute__((address_space(1))) unsigned int*)g,
        (__attribute__((address_space(3))) unsigned int*)l, 16, 0, 0);
}

// ---------------- W generation (fragment layout) + out zeroing ---------------
// Fragment (n16, kc) holds W[n16*16 + (l&15)][kc*32 + (l>>4)*8 + e] at
// shorts offset ((n16*98 + kc)*64 + l)*8 + e. (unchanged — passed 6 rounds)
__global__ __launch_bounds__(256) void gen_W(unsigned short* __restrict__ Wt,
                                             float4* __restrict__ outZ,
                                             int nvec4) {
    __shared__ float costab[512];
    __shared__ __align__(16) unsigned short rowbuf[KP];   // 6272 B
    const int l   = blockIdx.x;     // 0..639  (row n = l)
    const int tid = threadIdx.x;
    const float w0 = 6.283185307179586f / 512.0f;

    // zero the output buffer in-kernel (atomic epilogue needs it)
    for (int i = blockIdx.x * 256 + tid; i < nvec4; i += NP * 256)
        outZ[i] = make_float4(0.f, 0.f, 0.f, 0.f);

    *(int4*)(rowbuf + tid * 8) = make_int4(0, 0, 0, 0);
    if (tid < 136) *(int4*)(rowbuf + (256 + tid) * 8) = make_int4(0, 0, 0, 0);
    costab[tid]       = __cosf((float)tid * w0);
    costab[tid + 256] = __cosf((float)(tid + 256) * w0);
    __syncthreads();

    if (l < NOUT) {
        const int p = l + 256;
        float env = 0.0f;
#pragma unroll
        for (int tt = 0; tt < 6; ++tt) {
            int m = p - HOP * tt;
            if (m >= 0 && m < NFFT) {
                float w = 0.5f - 0.5f * costab[m];
                env += w * w;
            }
        }
        const float inv = 1.0f / (512.0f * env);
        for (int f = tid; f <= 256; f += 256) {
            float cf = (f == 0 || f == 256) ? 1.0f : 2.0f;
#pragma unroll
            for (int t = 0; t < 6; ++t) {
                int n = p - HOP * t;
                if (n >= 0 && n < NFFT) {
                    float w = 0.5f - 0.5f * costab[n];
                    float scale = cf * w * inv;
                    int a = (f * n) & 511;
                    float c = costab[a];
                    float s = costab[(a + 384) & 511];
                    rowbuf[f * 12 + t * 2 + 0] = bf16_bits(scale * c);
                    rowbuf[f * 12 + t * 2 + 1] = bf16_bits(-scale * s);
                }
            }
        }
    }
    __syncthreads();

    const int n16 = l >> 4, r = l & 15;
    for (int u = tid; u < 392; u += 256) {
        const int kc = u >> 2, q = u & 3;
        int4 val = *(const int4*)(rowbuf + kc * 32 + q * 8);
        *(int4*)(Wt + (((size_t)n16 * NFRAG_K + kc) * 64 + q * 16 + r) * 8) = val;
    }
}

// ---------------- GEMM: out += X * W^T (split-K = 2, 4-deep DMA) -------------
// 256 thr = 4 waves, wave tile 32(m) x 64(n); grid 1280 = 128mt x 5nt x 2k.
// LDS: 4 sets x 16KB. Set: A [64 rows][8 slots of 16B] fp32 (XOR-swizzled
// slots, swizzle applied on the per-lane GLOBAL source) + B = 8 W fragments.
__global__ __launch_bounds__(256, 2) void gemm_kernel(
        const float* __restrict__ X,           // fp32 [8192][3084]
        const unsigned short* __restrict__ Wt, // bf16 frags, WTOT shorts
        float* __restrict__ out) {             // fp32 [8192][600], pre-zeroed
    __shared__ __align__(16) unsigned char LDSc[4 * 16384];  // 65536 B

    const int tid = threadIdx.x;
    const int bid  = blockIdx.x;           // 0..1279
    const int xcd  = bid & 7;
    const int rest = bid >> 3;             // 0..159
    const int mt   = xcd * 16 + rest / 10; // 0..127
    const int sub  = rest % 10;
    const int nt   = sub >> 1;             // 0..4
    const int kidx = sub & 1;              // 0/1
    const int mBase = mt * BM;
    const int nBase = nt * BN;
    const int sBeg  = kidx * NT;           // BK=32 steps: [0,48) or [48,96)

    const int lane = tid & 63;
    const int wave = tid >> 6;
    const int wm   = (wave & 1) * 32;
    const int wn2  = (wave >> 1) * 64;
    const int lrow = lane & 15;
    const int quad = lane >> 4;

    // ---- A DMA source map (2 units/wave, u16 = wave*2 + uu):
    // unit covers rows [u16*8, u16*8+8), 8 lanes/row, 8 slots of 16B/row.
    // phys slot (lane&7) holds logical slot (lane&7)^(row&7)  [rule 21].
    const int grow0 = (wave * 2 + 0) * 8 + (lane >> 3);
    const int grow1 = (wave * 2 + 1) * 8 + (lane >> 3);
    const float* aSrc0 = X + (size_t)(mBase + grow0) * KDIM
                           + (((lane & 7) ^ (grow0 & 7)) * 4);
    const float* aSrc1 = X + (size_t)(mBase + grow1) * KDIM
                           + (((lane & 7) ^ (grow1 & 7)) * 4);

    // ---- B DMA source map (2 units/wave, j = wave*2 + jj): fragment
    // (n16 = nt*8 + j, kc = s), 1KB contiguous, per-lane src + lane*16B.
    const unsigned short* bSrc0 = Wt + ((size_t)(nt * 8 + wave * 2 + 0)
                                        * NFRAG_K) * FRAG_SH + (size_t)lane * 8;
    const unsigned short* bSrc1 = Wt + ((size_t)(nt * 8 + wave * 2 + 1)
                                        * NFRAG_K) * FRAG_SH + (size_t)lane * 8;

    // register-path B base (K tail only)
    const int n16base = nt * 8 + (wave >> 1) * 4;
    const unsigned short* wB0 = Wt + (size_t)n16base * NFRAG_K * FRAG_SH
                                   + (size_t)lane * 8;

#define DMA_SET(set_, s_)                                                      \
    {                                                                          \
        char* aDst = (char*)LDSc + (set_) * 16384;                             \
        char* bDst = aDst + 8192;                                              \
        gload_lds16(aSrc0 + (size_t)(s_) * 32, aDst + (wave * 2 + 0) * 1024);  \
        gload_lds16(aSrc1 + (size_t)(s_) * 32, aDst + (wave * 2 + 1) * 1024);  \
        gload_lds16(bSrc0 + (size_t)(s_) * FRAG_SH,                            \
                    bDst + (wave * 2 + 0) * 1024);                             \
        gload_lds16(bSrc1 + (size_t)(s_) * FRAG_SH,                            \
                    bDst + (wave * 2 + 1) * 1024);                             \
    }

    f32x4 acc[2][4];
#pragma unroll
    for (int i = 0; i < 2; ++i)
#pragma unroll
        for (int j = 0; j < 4; ++j) acc[i][j] = (f32x4){0.f, 0.f, 0.f, 0.f};

#define COMPUTE_SET(set_)                                                      \
    {                                                                          \
        const char* aB = (const char*)LDSc + (set_) * 16384;                   \
        const char* bB = aB + 8192;                                            \
        s16x8 bfr[4];                                                          \
        _Pragma("unroll")                                                      \
        for (int jj = 0; jj < 4; ++jj)                                         \
            bfr[jj] = *(const s16x8*)(const void*)(bB +                        \
                          ((wave >> 1) * 4 + jj) * 1024 + lane * 16);          \
        _Pragma("unroll")                                                      \
        for (int i = 0; i < 2; ++i) {                                          \
            const int R_ = wm + i * 16 + lrow;                                 \
            const int x_ = R_ & 7;                                             \
            float4 f0_ = *(const float4*)(aB + R_ * 128 +                      \
                             (((quad * 2) ^ x_) * 16));                        \
            float4 f1_ = *(const float4*)(aB + R_ * 128 +                      \
                             (((quad * 2 + 1) ^ x_) * 16));                    \
            s16x8 af_ = cvt_frag(f0_, f1_);                                    \
            _Pragma("unroll")                                                  \
            for (int jj = 0; jj < 4; ++jj)                                     \
                acc[i][jj] = __builtin_amdgcn_mfma_f32_16x16x32_bf16(          \
                    af_, bfr[jj], acc[i][jj], 0, 0, 0);                        \
        }                                                                      \
    }

    // ---- prologue: fill sets 0,1,2 (depth 3 in flight; 4th set filled in-loop)
    DMA_SET(0, sBeg + 0);
    DMA_SET(1, sBeg + 1);
    DMA_SET(2, sBeg + 2);

    for (int t = 0; t < NT; ++t) {
        // wait: D(t) landed. Newer per-wave ops: D(t+1),D(t+2) as issued.
        if (t <= NT - 3)      asm volatile("s_waitcnt vmcnt(8) lgkmcnt(0)" ::: "memory");
        else if (t == NT - 2) asm volatile("s_waitcnt vmcnt(4) lgkmcnt(0)" ::: "memory");
        else                  asm volatile("s_waitcnt vmcnt(0) lgkmcnt(0)" ::: "memory");
        __builtin_amdgcn_s_barrier();       // all waves: D(t) landed, old reads done
        __builtin_amdgcn_sched_barrier(0);  // pin: nothing moves above
        if (t + 3 < NT) DMA_SET((t + 3) & 3, sBeg + t + 3);  // set freed at t-1
        COMPUTE_SET(t & 3);
    }

    // ---- K tail: kc = 96 (k 3072..3103, guard vs KDIM), kidx==1 only.
    // Register path (passed 3 rounds). kc=97: W zero-pad, skipped.
    if (kidx) {
        const float* aRow0 = X + (size_t)(mBase + wm + lrow) * KDIM;
        const float* aRow1 = aRow0 + (size_t)16 * KDIM;
        const int kb = 96 * 32 + quad * 8;
        float e0[8], e1[8];
#pragma unroll
        for (int e = 0; e < 8; ++e) {
            const int k = kb + e;
            const bool ok = (k < KDIM);
            e0[e] = ok ? aRow0[k] : 0.f;
            e1[e] = ok ? aRow1[k] : 0.f;
        }
        float4 l0 = make_float4(e0[0], e0[1], e0[2], e0[3]);
        float4 h0 = make_float4(e0[4], e0[5], e0[6], e0[7]);
        float4 l1 = make_float4(e1[0], e1[1], e1[2], e1[3]);
        float4 h1 = make_float4(e1[4], e1[5], e1[6], e1[7]);
        s16x8 bvt[4];
#pragma unroll
        for (int j = 0; j < 4; ++j)
            bvt[j] = *(const s16x8*)(const void*)(wB0 +
                         ((size_t)j * NFRAG_K + 96) * FRAG_SH);
        s16x8 af0 = cvt_frag(l0, h0);
        s16x8 af1 = cvt_frag(l1, h1);
#pragma unroll
        for (int j = 0; j < 4; ++j)
            acc[0][j] = __builtin_amdgcn_mfma_f32_16x16x32_bf16(
                af0, bvt[j], acc[0][j], 0, 0, 0);
#pragma unroll
        for (int j = 0; j < 4; ++j)
            acc[1][j] = __builtin_amdgcn_mfma_f32_16x16x32_bf16(
                af1, bvt[j], acc[1][j], 0, 0, 0);
    }

#undef DMA_SET
#undef COMPUTE_SET

    // ---- epilogue: H1 layout (n=lane&15, m=quad*4+reg), atomic accumulate
#pragma unroll
    for (int i = 0; i < 2; ++i) {
#pragma unroll
        for (int j = 0; j < 4; ++j) {
            int gn = nBase + wn2 + j * 16 + lrow;
            if (gn < NOUT) {
#pragma unroll
                for (int r = 0; r < 4; ++r) {
                    int gm = mBase + wm + i * 16 + quad * 4 + r;
                    atomicAdd(out + (size_t)gm * NOUT + gn, acc[i][j][r]);
                }
            }
        }
    }
}

extern "C" void kernel_launch(void* const* d_in, const int* in_sizes, int n_in,
                              void* d_out, int out_size, void* d_ws, size_t ws_size,
                              hipStream_t stream) {
    const float* X = (const float*)d_in[0];
    unsigned short* W = (unsigned short*)d_ws;   // bf16 fragment layout, 4.01 MB
    float* out = (float*)d_out;

    gen_W<<<dim3(NP), 256, 0, stream>>>(W, (float4*)d_out, out_size / 4);
    gemm_kernel<<<dim3(GRIDB), 256, 0, stream>>>(X, W, out);
}